// Round 20
// baseline (101.158 us; speedup 1.0000x reference)
//
#include <hip/hip_runtime.h>
#include <stdint.h>

typedef unsigned short u16;
typedef short bfrag __attribute__((ext_vector_type(8)));   // 8 bf16 (4 VGPR) MFMA A/B frag
typedef float ffrag __attribute__((ext_vector_type(4)));   // 4 f32 MFMA C/D frag
typedef u16 us4 __attribute__((ext_vector_type(4)));
typedef uint32_t u32x4 __attribute__((ext_vector_type(4)));

#define HW 1024
#define C_DIM 512
#define O3 1536
#define BATCH 16

__device__ __forceinline__ u16 f2bf(float f) {
    uint32_t u = __builtin_bit_cast(uint32_t, f);
    u += 0x7FFFu + ((u >> 16) & 1u);           // RNE
    return (u16)(u >> 16);
}
__device__ __forceinline__ float bf2f(u16 v) {
    return __builtin_bit_cast(float, (uint32_t)v << 16);
}
__device__ __forceinline__ float fexp2(float x) { return __builtin_amdgcn_exp2f(x); }
__device__ __forceinline__ void async16(const u16* src, u16* ldsDst) {
    __builtin_amdgcn_global_load_lds(
        (const __attribute__((address_space(1))) uint32_t*)src,
        (__attribute__((address_space(3))) uint32_t*)ldsDst, 16, 0, 0);
}

// ---------------- GroupNorm (blocks 0..511) + weight cvt (blocks 512..1535) -----------
__global__ __launch_bounds__(256) void gn_cvt_kernel(
    const float* __restrict__ x, const float* __restrict__ gw, const float* __restrict__ gb,
    u16* __restrict__ xgt,
    const float* __restrict__ qkvw, u16* __restrict__ qkvwb,
    const float* __restrict__ projw, u16* __restrict__ projwb)
{
    __shared__ u16 tile[16 * 1032];
    __shared__ float red[8];
    const int tid = threadIdx.x;
    if (blockIdx.x >= 512) {
        int i = (blockIdx.x - 512) * 256 + tid;
        if (i < 196608) {
            float4 v = ((const float4*)qkvw)[i];
            us4 o = { f2bf(v.x), f2bf(v.y), f2bf(v.z), f2bf(v.w) };
            ((us4*)qkvwb)[i] = o;
        } else {
            int j = i - 196608;
            float4 v = ((const float4*)projw)[j];
            us4 o = { f2bf(v.x), f2bf(v.y), f2bf(v.z), f2bf(v.w) };
            ((us4*)projwb)[j] = o;
        }
        return;
    }
    const int batch = blockIdx.x >> 5, g = blockIdx.x & 31;
    const float* xp = x + ((size_t)batch * C_DIM + g * 16) * HW;

    float s = 0.f, ss = 0.f;
#pragma unroll
    for (int it = 0; it < 16; ++it) {
        int i4 = it * 256 + tid;
        float4 v = ((const float4*)xp)[i4];
        int ci = i4 >> 8;
        int hw = (i4 & 255) * 4;
        s += v.x + v.y + v.z + v.w;
        ss += v.x * v.x + v.y * v.y + v.z * v.z + v.w * v.w;
        us4 u = { f2bf(v.x), f2bf(v.y), f2bf(v.z), f2bf(v.w) };
        *(us4*)&tile[ci * 1032 + hw] = u;
    }
#pragma unroll
    for (int m = 1; m <= 32; m <<= 1) { s += __shfl_xor(s, m, 64); ss += __shfl_xor(ss, m, 64); }
    if ((tid & 63) == 0) { red[tid >> 6] = s; red[4 + (tid >> 6)] = ss; }
    __syncthreads();
    float S = red[0] + red[1] + red[2] + red[3];
    float SS = red[4] + red[5] + red[6] + red[7];
    const float mean = S * (1.f / 16384.f);
    const float istd = rsqrtf(SS * (1.f / 16384.f) - mean * mean + 1e-5f);

    u16* xtp = xgt + (size_t)batch * HW * C_DIM + g * 16;
#pragma unroll
    for (int it = 0; it < 16; ++it) {
        int hw = (tid >> 2) + it * 64;
        int c0 = (tid & 3) * 4;
        us4 o;
#pragma unroll
        for (int k2 = 0; k2 < 4; ++k2) {
            int ci = c0 + k2;
            float sc = gw[g * 16 + ci] * istd;
            float bi = gb[g * 16 + ci] - mean * sc;
            o[k2] = f2bf(bf2f(tile[ci * 1032 + hw]) * sc + bi);
        }
        *(us4*)&xtp[(size_t)hw * C_DIM + c0] = o;
    }
}

// ---------------- QKV GEMM: 128x128 tile, BK=64, double-buffered (64KB) ---------------
// Q columns (tn<4) are pre-scaled by cexp = 0.125*log2(e).
__global__ __launch_bounds__(256) void qkv_gemm_kernel(
    const u16* __restrict__ A, const u16* __restrict__ B, u16* __restrict__ Out,
    u16* __restrict__ vtout)
{
    __shared__ __align__(16) u16 smem[32768];   // A0@0 A1@8192 | B0@16384 B1@24576 (64KB)
    const int tid = threadIdx.x;
    const int l = tid & 63, w = tid >> 6;
    const int swz = (blockIdx.x & 7) * 192 + (blockIdx.x >> 3);   // 1536 blocks
    const int batch = swz / 96, t = swz % 96;
    const int tm = t / 12, tn = t % 12;
    A += (size_t)batch * (HW * C_DIM) + (size_t)tm * 128 * 512;
    B += (size_t)tn * 128 * 512;

    auto stage = [&](const u16* gbase, u16* lds, int kt) {
#pragma unroll
        for (int i = 0; i < 4; ++i) {
            int L = i * 256 + tid;
            int row = L >> 3, cs = L & 7;
            int c = cs ^ (row & 7);
            async16(gbase + (size_t)row * 512 + kt * 64 + c * 8,
                    lds + (size_t)(i * 256 + (tid & 192)) * 8);
        }
    };

    ffrag acc[4][4] = {};
    stage(A, smem, 0); stage(B, smem + 16384, 0);
    const int wr = (w >> 1) * 64, wc = (w & 1) * 64;
#pragma unroll
    for (int kt = 0; kt < 8; ++kt) {
        const int cur = kt & 1;
        asm volatile("s_waitcnt vmcnt(0)" ::: "memory");
        __builtin_amdgcn_s_barrier();
        __builtin_amdgcn_sched_barrier(0);
        if (kt < 7) {
            stage(A, smem + (cur ^ 1) * 8192, kt + 1);
            stage(B, smem + 16384 + (cur ^ 1) * 8192, kt + 1);
        }
        const u16* As = smem + cur * 8192;
        const u16* Bs = smem + 16384 + cur * 8192;
#pragma unroll
        for (int kc = 0; kc < 2; ++kc) {
            bfrag a[4], bb[4];
#pragma unroll
            for (int i = 0; i < 4; ++i) {
                int row = wr + i * 16 + (l & 15);
                int ch = (kc * 4 + (l >> 4)) ^ (row & 7);
                a[i] = *(const bfrag*)&As[row * 64 + ch * 8];
                int col = wc + i * 16 + (l & 15);
                int ch2 = (kc * 4 + (l >> 4)) ^ (col & 7);
                bb[i] = *(const bfrag*)&Bs[col * 64 + ch2 * 8];
            }
            __builtin_amdgcn_s_setprio(1);
#pragma unroll
            for (int i = 0; i < 4; ++i)
#pragma unroll
                for (int j = 0; j < 4; ++j)
                    acc[i][j] = __builtin_amdgcn_mfma_f32_16x16x32_bf16(a[i], bb[j], acc[i][j], 0, 0, 0);
            __builtin_amdgcn_s_setprio(0);
        }
    }
    __syncthreads();
    const int rbase = tm * 128 + wr + ((l >> 4) << 2);
    const int cbase = tn * 128 + wc + (l & 15);
    if (tn < 8) {
        const float oscale = (tn < 4) ? 0.1803368801f : 1.0f;
        u16* outp = Out + (size_t)batch * (HW * O3);
#pragma unroll
        for (int i = 0; i < 4; ++i)
#pragma unroll
            for (int j = 0; j < 4; ++j)
#pragma unroll
                for (int r = 0; r < 4; ++r)
                    outp[(size_t)(rbase + i * 16 + r) * O3 + cbase + j * 16] =
                        f2bf(acc[i][j][r] * oscale);
    } else {
        u16* vb = vtout + (size_t)batch * 8 * 64 * HW;
        const int hd0 = tn * 128 - 1024;
#pragma unroll
        for (int i = 0; i < 4; ++i)
#pragma unroll
            for (int j = 0; j < 4; ++j) {
                int hd_l = wc + (l & 15) + j * 16;
                int m_l = wr + i * 16 + ((l >> 4) << 2);
                int s_l = (m_l & 96) | ((m_l & 12) << 1) | ((m_l & 16) >> 2);
                int c4 = s_l >> 2;
                int c4s = c4 ^ (hd_l & 7);
                us4 pk = { f2bf(acc[i][j][0]), f2bf(acc[i][j][1]),
                           f2bf(acc[i][j][2]), f2bf(acc[i][j][3]) };
                *(us4*)&smem[hd_l * 128 + c4s * 4] = pk;
            }
        __syncthreads();
#pragma unroll
        for (int it = 0; it < 16; ++it) {
            int f4 = it * 256 + tid;
            int hd_l = f4 >> 5, c4 = f4 & 31;
            int c4s = c4 ^ (hd_l & 7);
            us4 v = *(const us4*)&smem[hd_l * 128 + c4s * 4];
            *(us4*)&vb[(size_t)(hd0 + hd_l) * HW + tm * 128 + c4 * 4] = v;
        }
    }
}

// ---------------- proj GEMM: 128x128, BK=64 double-buffered, f32+bias+residT ----------
__global__ __launch_bounds__(256) void proj_gemm_kernel(
    const u16* __restrict__ A, const u16* __restrict__ B, float* __restrict__ Out,
    const float* __restrict__ bias, const u16* __restrict__ residT)
{
    __shared__ __align__(16) u16 smem[32768];   // A0@0 A1@8192 | B0@16384 B1@24576 (64KB)
    const int tid = threadIdx.x;
    const int l = tid & 63, w = tid >> 6;
    const int swz = (blockIdx.x & 7) * 64 + (blockIdx.x >> 3);
    const int batch = swz / 32, t = swz % 32;
    const int tm = t / 8, tn = t % 8;
    A += (size_t)tm * 128 * 512;
    B += (size_t)batch * (HW * C_DIM) + (size_t)tn * 128 * 512;

    auto stage = [&](const u16* gbase, u16* lds, int kt) {
#pragma unroll
        for (int i = 0; i < 4; ++i) {
            int L = i * 256 + tid;
            int row = L >> 3, cs = L & 7;
            int c = cs ^ (row & 7);
            async16(gbase + (size_t)row * 512 + kt * 64 + c * 8,
                    lds + (size_t)(i * 256 + (tid & 192)) * 8);
        }
    };

    ffrag acc[4][4] = {};
    stage(A, smem, 0); stage(B, smem + 16384, 0);
    const int wr = (w >> 1) * 64, wc = (w & 1) * 64;
#pragma unroll
    for (int kt = 0; kt < 8; ++kt) {
        const int cur = kt & 1;
        asm volatile("s_waitcnt vmcnt(0)" ::: "memory");
        __builtin_amdgcn_s_barrier();
        __builtin_amdgcn_sched_barrier(0);
        if (kt < 7) {
            stage(A, smem + (cur ^ 1) * 8192, kt + 1);
            stage(B, smem + 16384 + (cur ^ 1) * 8192, kt + 1);
        }
        const u16* As = smem + cur * 8192;
        const u16* Bs = smem + 16384 + cur * 8192;
#pragma unroll
        for (int kc = 0; kc < 2; ++kc) {
            bfrag a[4], bb[4];
#pragma unroll
            for (int i = 0; i < 4; ++i) {
                int row = wr + i * 16 + (l & 15);
                int ch = (kc * 4 + (l >> 4)) ^ (row & 7);
                a[i] = *(const bfrag*)&As[row * 64 + ch * 8];
                int col = wc + i * 16 + (l & 15);
                int ch2 = (kc * 4 + (l >> 4)) ^ (col & 7);
                bb[i] = *(const bfrag*)&Bs[col * 64 + ch2 * 8];
            }
            __builtin_amdgcn_s_setprio(1);
#pragma unroll
            for (int i = 0; i < 4; ++i)
#pragma unroll
                for (int j = 0; j < 4; ++j)
                    acc[i][j] = __builtin_amdgcn_mfma_f32_16x16x32_bf16(a[i], bb[j], acc[i][j], 0, 0, 0);
            __builtin_amdgcn_s_setprio(0);
        }
    }
    const int rbase = tm * 128 + wr + ((l >> 4) << 2);
    const int cbase = tn * 128 + wc + (l & 15);
    float* outp = Out + (size_t)batch * (C_DIM * HW);
    const u16* rt = residT + (size_t)batch * (HW * C_DIM);
#pragma unroll
    for (int i = 0; i < 4; ++i)
#pragma unroll
        for (int j = 0; j < 4; ++j) {
            int cc = cbase + j * 16;                       // hw
            us4 rv = *(const us4*)&rt[(size_t)cc * C_DIM + rbase + i * 16];
#pragma unroll
            for (int r = 0; r < 4; ++r) {
                int rr = rbase + i * 16 + r;               // out channel
                outp[(size_t)rr * HW + cc] = acc[i][j][r] + bias[rr] + bf2f(rv[r]);
            }
        }
}

// ---------------- Flash attention: 2 m-tiles/step + counted split drains --------------
// Step s processes tiles 2s,2s+1 (slots {0,1} or {2,3}); stages 2s+2,2s+3 into the
// other slot pair. DMA issue order K(2s),V(2s),K(2s+1),V(2s+1) => at step-top
// vmcnt(2) completes tile 2s only (2s+1's pair stays in flight across the barrier);
// after issuing 4 new DMAs, vmcnt(4) completes tile 2s+1 before its half.
__global__ __launch_bounds__(512, 4) void attn_kernel(const u16* __restrict__ qkvt,
                                                      const u16* __restrict__ vt,
                                                      u16* __restrict__ ht)
{
    __shared__ __align__(16) u16 KVs[8 * 4096];
    const int tid = threadIdx.x, l = tid & 63, w = tid >> 6, g = l >> 4;
    const int swz = ((blockIdx.x & 7) << 6) + (blockIdx.x >> 3);
    const int nt = swz & 3, h = (swz >> 2) & 7, batch = swz >> 5;
    const u16* Qb = qkvt + (size_t)batch * HW * O3 + h * 64;
    const u16* Kb = Qb + 512;
    const u16* Vtb = vt + (size_t)(batch * 8 + h) * 64 * HW;
    const int n0 = nt * 256 + w * 32;

    bfrag qf[2][2];
#pragma unroll
    for (int ni = 0; ni < 2; ++ni)
#pragma unroll
        for (int kc = 0; kc < 2; ++kc)
            qf[ni][kc] = *(const bfrag*)&Qb[(size_t)(n0 + ni * 16 + (l & 15)) * O3 + kc * 32 + g * 8];

    bfrag ones;
#pragma unroll
    for (int k = 0; k < 8; ++k) ones[k] = (short)0x3F80;   // bf16 1.0

    auto stageK = [&](int ms, u16* lds) {
        int row = tid >> 3, c = (tid & 7) ^ (row & 7);
        async16(&Kb[(size_t)(ms * 64 + row) * O3 + c * 8], lds + (size_t)(tid & 448) * 8);
    };
    auto stageV = [&](int ms, u16* lds) {
        int row = tid >> 3, c = (tid & 7) ^ (row & 7);
        async16(&Vtb[(size_t)row * HW + ms * 64 + c * 8], lds + (size_t)(tid & 448) * 8);
    };

    ffrag hacc[2][4] = {};
    ffrag accl[2] = {};

    stageK(0, KVs);        stageV(0, KVs + 4 * 4096);
    stageK(1, KVs + 4096); stageV(1, KVs + 5 * 4096);

#pragma unroll
    for (int st = 0; st < 8; ++st) {
        // tile 2st complete; tile 2st+1's 2 DMAs may remain in flight across the barrier
        asm volatile("s_waitcnt vmcnt(2)" ::: "memory");
        __builtin_amdgcn_s_barrier();
        __builtin_amdgcn_sched_barrier(0);
        if (st < 7) {
            const int mt2 = 2 * st + 2, mt3 = 2 * st + 3;
            stageK(mt2, KVs + (mt2 & 3) * 4096);
            stageV(mt2, KVs + (4 + (mt2 & 3)) * 4096);
            stageK(mt3, KVs + (mt3 & 3) * 4096);
            stageV(mt3, KVs + (4 + (mt3 & 3)) * 4096);
        }
#pragma unroll
        for (int half = 0; half < 2; ++half) {
            const int mt = 2 * st + half;
            const u16* Ksc = KVs + (mt & 3) * 4096;
            const u16* Vsc = KVs + (4 + (mt & 3)) * 4096;
            if (half == 1) {
                // complete tile 2st+1 (4 newly staged DMAs remain outstanding)
                if (st < 7) asm volatile("s_waitcnt vmcnt(4)" ::: "memory");
                else        asm volatile("s_waitcnt vmcnt(0)" ::: "memory");
                __builtin_amdgcn_sched_barrier(0);
            }

            ffrag s[2][4] = {};
            __builtin_amdgcn_s_setprio(1);
#pragma unroll
            for (int mj = 0; mj < 4; ++mj)
#pragma unroll
                for (int kc = 0; kc < 2; ++kc) {
                    int m = mj * 16 + (l & 15);
                    int ch = (kc * 4 + g) ^ (m & 7);
                    bfrag kf = *(const bfrag*)&Ksc[m * 64 + ch * 8];
#pragma unroll
                    for (int ni = 0; ni < 2; ++ni)
                        s[ni][mj] = __builtin_amdgcn_mfma_f32_16x16x32_bf16(kf, qf[ni][kc], s[ni][mj], 0, 0, 0);
                }
            __builtin_amdgcn_s_setprio(0);

            // S pre-scaled by cexp (folded into Q): P = exp2(S)
            u32x4 pk[2][2];
#pragma unroll
            for (int ni = 0; ni < 2; ++ni)
#pragma unroll
                for (int kc = 0; kc < 2; ++kc)
#pragma unroll
                    for (int hh = 0; hh < 2; ++hh) {
                        int mj = kc * 2 + hh;
                        float p0 = fexp2(s[ni][mj][0]);
                        float p1 = fexp2(s[ni][mj][1]);
                        float p2 = fexp2(s[ni][mj][2]);
                        float p3 = fexp2(s[ni][mj][3]);
                        pk[ni][kc][hh * 2] = __builtin_amdgcn_perm(
                            __builtin_bit_cast(uint32_t, p1), __builtin_bit_cast(uint32_t, p0), 0x07060302u);
                        pk[ni][kc][hh * 2 + 1] = __builtin_amdgcn_perm(
                            __builtin_bit_cast(uint32_t, p3), __builtin_bit_cast(uint32_t, p2), 0x07060302u);
                    }

            __builtin_amdgcn_s_setprio(1);
#pragma unroll
            for (int kc = 0; kc < 2; ++kc) {
                bfrag pf0 = __builtin_bit_cast(bfrag, pk[0][kc]);
                bfrag pf1 = __builtin_bit_cast(bfrag, pk[1][kc]);
                accl[0] = __builtin_amdgcn_mfma_f32_16x16x32_bf16(pf0, ones, accl[0], 0, 0, 0);
                accl[1] = __builtin_amdgcn_mfma_f32_16x16x32_bf16(pf1, ones, accl[1], 0, 0, 0);
#pragma unroll
                for (int dj = 0; dj < 4; ++dj) {
                    int d = dj * 16 + (l & 15);
                    int ch = (kc * 4 + g) ^ (d & 7);
                    bfrag vf = *(const bfrag*)&Vsc[d * 64 + ch * 8];
                    hacc[0][dj] = __builtin_amdgcn_mfma_f32_16x16x32_bf16(pf0, vf, hacc[0][dj], 0, 0, 0);
                    hacc[1][dj] = __builtin_amdgcn_mfma_f32_16x16x32_bf16(pf1, vf, hacc[1][dj], 0, 0, 0);
                }
            }
            __builtin_amdgcn_s_setprio(0);
        }
    }

    // epilogue: h_t[b][n][h*64+d]
    u16* hp = ht + (size_t)batch * HW * C_DIM + h * 64;
#pragma unroll
    for (int ni = 0; ni < 2; ++ni) {
        float linv[4];
#pragma unroll
        for (int r = 0; r < 4; ++r) linv[r] = __builtin_amdgcn_rcpf(accl[ni][r]);
#pragma unroll
        for (int dj = 0; dj < 4; ++dj)
#pragma unroll
            for (int r = 0; r < 4; ++r) {
                int n = n0 + ni * 16 + g * 4 + r;
                int d = dj * 16 + (l & 15);
                hp[(size_t)n * C_DIM + d] = f2bf(hacc[ni][dj][r] * linv[r]);
            }
    }
}

extern "C" void kernel_launch(void* const* d_in, const int* in_sizes, int n_in,
                              void* d_out, int out_size, void* d_ws, size_t ws_size,
                              hipStream_t stream)
{
    const float* x = (const float*)d_in[0];
    const float* gw = (const float*)d_in[1];
    const float* gb = (const float*)d_in[2];
    const float* qkvw = (const float*)d_in[3];
    const float* projw = (const float*)d_in[4];
    const float* projb = (const float*)d_in[5];
    float* out = (float*)d_out;
    char* ws = (char*)d_ws;
    u16* ht    = (u16*)(ws);               // 16.78 MB  [B][HW][C]  attn output
    u16* xgt   = (u16*)(ws + 16777216);    // 16.78 MB  [B][HW][C]  normed x (lives to proj)
    u16* qkvt  = (u16*)(ws + 33554432);    // 50.33 MB  [B][HW][1536] (V third unused)
    u16* vt    = (u16*)(ws + 83886080);    // 16.78 MB  [B*8][64][1024] sigma-permuted cols
    u16* qkvwb = (u16*)(ws + 100663296);   // 1.57 MB
    u16* projwb= (u16*)(ws + 102236160);   // 0.52 MB

    gn_cvt_kernel<<<1536, 256, 0, stream>>>(x, gw, gb, xgt, qkvw, qkvwb, projw, projwb);
    qkv_gemm_kernel<<<1536, 256, 0, stream>>>(xgt, qkvwb, qkvt, vt);
    attn_kernel<<<512, 512, 0, stream>>>(qkvt, vt, ht);
    proj_gemm_kernel<<<512, 256, 0, stream>>>(projwb, ht, out, projb, xgt);
}

// Round 21
// 100.473 us; speedup vs baseline: 1.0068x; 1.0068x over previous
//
#include <hip/hip_runtime.h>
#include <stdint.h>

typedef unsigned short u16;
typedef short bfrag __attribute__((ext_vector_type(8)));   // 8 bf16 (4 VGPR) MFMA A/B frag
typedef float ffrag __attribute__((ext_vector_type(4)));   // 4 f32 MFMA C/D frag
typedef u16 us4 __attribute__((ext_vector_type(4)));
typedef uint32_t u32x4 __attribute__((ext_vector_type(4)));

#define HW 1024
#define C_DIM 512
#define O3 1536
#define BATCH 16

__device__ __forceinline__ u16 f2bf(float f) {
    uint32_t u = __builtin_bit_cast(uint32_t, f);
    u += 0x7FFFu + ((u >> 16) & 1u);           // RNE
    return (u16)(u >> 16);
}
__device__ __forceinline__ float bf2f(u16 v) {
    return __builtin_bit_cast(float, (uint32_t)v << 16);
}
__device__ __forceinline__ float fexp2(float x) { return __builtin_amdgcn_exp2f(x); }
__device__ __forceinline__ void async16(const u16* src, u16* ldsDst) {
    __builtin_amdgcn_global_load_lds(
        (const __attribute__((address_space(1))) uint32_t*)src,
        (__attribute__((address_space(3))) uint32_t*)ldsDst, 16, 0, 0);
}

// ---------------- GroupNorm (blocks 0..511) + weight cvt (blocks 512..1535) -----------
__global__ __launch_bounds__(256) void gn_cvt_kernel(
    const float* __restrict__ x, const float* __restrict__ gw, const float* __restrict__ gb,
    u16* __restrict__ xgt,
    const float* __restrict__ qkvw, u16* __restrict__ qkvwb,
    const float* __restrict__ projw, u16* __restrict__ projwb)
{
    __shared__ u16 tile[16 * 1032];
    __shared__ float red[8];
    const int tid = threadIdx.x;
    if (blockIdx.x >= 512) {
        int i = (blockIdx.x - 512) * 256 + tid;
        if (i < 196608) {
            float4 v = ((const float4*)qkvw)[i];
            us4 o = { f2bf(v.x), f2bf(v.y), f2bf(v.z), f2bf(v.w) };
            ((us4*)qkvwb)[i] = o;
        } else {
            int j = i - 196608;
            float4 v = ((const float4*)projw)[j];
            us4 o = { f2bf(v.x), f2bf(v.y), f2bf(v.z), f2bf(v.w) };
            ((us4*)projwb)[j] = o;
        }
        return;
    }
    const int batch = blockIdx.x >> 5, g = blockIdx.x & 31;
    const float* xp = x + ((size_t)batch * C_DIM + g * 16) * HW;

    float s = 0.f, ss = 0.f;
#pragma unroll
    for (int it = 0; it < 16; ++it) {
        int i4 = it * 256 + tid;
        float4 v = ((const float4*)xp)[i4];
        int ci = i4 >> 8;
        int hw = (i4 & 255) * 4;
        s += v.x + v.y + v.z + v.w;
        ss += v.x * v.x + v.y * v.y + v.z * v.z + v.w * v.w;
        us4 u = { f2bf(v.x), f2bf(v.y), f2bf(v.z), f2bf(v.w) };
        *(us4*)&tile[ci * 1032 + hw] = u;
    }
#pragma unroll
    for (int m = 1; m <= 32; m <<= 1) { s += __shfl_xor(s, m, 64); ss += __shfl_xor(ss, m, 64); }
    if ((tid & 63) == 0) { red[tid >> 6] = s; red[4 + (tid >> 6)] = ss; }
    __syncthreads();
    float S = red[0] + red[1] + red[2] + red[3];
    float SS = red[4] + red[5] + red[6] + red[7];
    const float mean = S * (1.f / 16384.f);
    const float istd = rsqrtf(SS * (1.f / 16384.f) - mean * mean + 1e-5f);

    u16* xtp = xgt + (size_t)batch * HW * C_DIM + g * 16;
#pragma unroll
    for (int it = 0; it < 16; ++it) {
        int hw = (tid >> 2) + it * 64;
        int c0 = (tid & 3) * 4;
        us4 o;
#pragma unroll
        for (int k2 = 0; k2 < 4; ++k2) {
            int ci = c0 + k2;
            float sc = gw[g * 16 + ci] * istd;
            float bi = gb[g * 16 + ci] - mean * sc;
            o[k2] = f2bf(bf2f(tile[ci * 1032 + hw]) * sc + bi);
        }
        *(us4*)&xtp[(size_t)hw * C_DIM + c0] = o;
    }
}

// ---------------- QKV GEMM: 128x128 tile, BK=64, double-buffered (64KB) ---------------
// Q columns (tn<4) are pre-scaled by cexp = 0.125*log2(e).
__global__ __launch_bounds__(256) void qkv_gemm_kernel(
    const u16* __restrict__ A, const u16* __restrict__ B, u16* __restrict__ Out,
    u16* __restrict__ vtout)
{
    __shared__ __align__(16) u16 smem[32768];   // A0@0 A1@8192 | B0@16384 B1@24576 (64KB)
    const int tid = threadIdx.x;
    const int l = tid & 63, w = tid >> 6;
    const int swz = (blockIdx.x & 7) * 192 + (blockIdx.x >> 3);   // 1536 blocks
    const int batch = swz / 96, t = swz % 96;
    const int tm = t / 12, tn = t % 12;
    A += (size_t)batch * (HW * C_DIM) + (size_t)tm * 128 * 512;
    B += (size_t)tn * 128 * 512;

    auto stage = [&](const u16* gbase, u16* lds, int kt) {
#pragma unroll
        for (int i = 0; i < 4; ++i) {
            int L = i * 256 + tid;
            int row = L >> 3, cs = L & 7;
            int c = cs ^ (row & 7);
            async16(gbase + (size_t)row * 512 + kt * 64 + c * 8,
                    lds + (size_t)(i * 256 + (tid & 192)) * 8);
        }
    };

    ffrag acc[4][4] = {};
    stage(A, smem, 0); stage(B, smem + 16384, 0);
    const int wr = (w >> 1) * 64, wc = (w & 1) * 64;
#pragma unroll
    for (int kt = 0; kt < 8; ++kt) {
        const int cur = kt & 1;
        asm volatile("s_waitcnt vmcnt(0)" ::: "memory");
        __builtin_amdgcn_s_barrier();
        __builtin_amdgcn_sched_barrier(0);
        if (kt < 7) {
            stage(A, smem + (cur ^ 1) * 8192, kt + 1);
            stage(B, smem + 16384 + (cur ^ 1) * 8192, kt + 1);
        }
        const u16* As = smem + cur * 8192;
        const u16* Bs = smem + 16384 + cur * 8192;
#pragma unroll
        for (int kc = 0; kc < 2; ++kc) {
            bfrag a[4], bb[4];
#pragma unroll
            for (int i = 0; i < 4; ++i) {
                int row = wr + i * 16 + (l & 15);
                int ch = (kc * 4 + (l >> 4)) ^ (row & 7);
                a[i] = *(const bfrag*)&As[row * 64 + ch * 8];
                int col = wc + i * 16 + (l & 15);
                int ch2 = (kc * 4 + (l >> 4)) ^ (col & 7);
                bb[i] = *(const bfrag*)&Bs[col * 64 + ch2 * 8];
            }
            __builtin_amdgcn_s_setprio(1);
#pragma unroll
            for (int i = 0; i < 4; ++i)
#pragma unroll
                for (int j = 0; j < 4; ++j)
                    acc[i][j] = __builtin_amdgcn_mfma_f32_16x16x32_bf16(a[i], bb[j], acc[i][j], 0, 0, 0);
            __builtin_amdgcn_s_setprio(0);
        }
    }
    __syncthreads();
    const int rbase = tm * 128 + wr + ((l >> 4) << 2);
    const int cbase = tn * 128 + wc + (l & 15);
    if (tn < 8) {
        const float oscale = (tn < 4) ? 0.1803368801f : 1.0f;
        u16* outp = Out + (size_t)batch * (HW * O3);
#pragma unroll
        for (int i = 0; i < 4; ++i)
#pragma unroll
            for (int j = 0; j < 4; ++j)
#pragma unroll
                for (int r = 0; r < 4; ++r)
                    outp[(size_t)(rbase + i * 16 + r) * O3 + cbase + j * 16] =
                        f2bf(acc[i][j][r] * oscale);
    } else {
        u16* vb = vtout + (size_t)batch * 8 * 64 * HW;
        const int hd0 = tn * 128 - 1024;
#pragma unroll
        for (int i = 0; i < 4; ++i)
#pragma unroll
            for (int j = 0; j < 4; ++j) {
                int hd_l = wc + (l & 15) + j * 16;
                int m_l = wr + i * 16 + ((l >> 4) << 2);
                int s_l = (m_l & 96) | ((m_l & 12) << 1) | ((m_l & 16) >> 2);
                int c4 = s_l >> 2;
                int c4s = c4 ^ (hd_l & 7);
                us4 pk = { f2bf(acc[i][j][0]), f2bf(acc[i][j][1]),
                           f2bf(acc[i][j][2]), f2bf(acc[i][j][3]) };
                *(us4*)&smem[hd_l * 128 + c4s * 4] = pk;
            }
        __syncthreads();
#pragma unroll
        for (int it = 0; it < 16; ++it) {
            int f4 = it * 256 + tid;
            int hd_l = f4 >> 5, c4 = f4 & 31;
            int c4s = c4 ^ (hd_l & 7);
            us4 v = *(const us4*)&smem[hd_l * 128 + c4s * 4];
            *(us4*)&vb[(size_t)(hd0 + hd_l) * HW + tm * 128 + c4 * 4] = v;
        }
    }
}

// ---------------- proj GEMM: 128x128, BK=64 double-buffered, f32+bias+residT ----------
__global__ __launch_bounds__(256) void proj_gemm_kernel(
    const u16* __restrict__ A, const u16* __restrict__ B, float* __restrict__ Out,
    const float* __restrict__ bias, const u16* __restrict__ residT)
{
    __shared__ __align__(16) u16 smem[32768];   // A0@0 A1@8192 | B0@16384 B1@24576 (64KB)
    const int tid = threadIdx.x;
    const int l = tid & 63, w = tid >> 6;
    const int swz = (blockIdx.x & 7) * 64 + (blockIdx.x >> 3);
    const int batch = swz / 32, t = swz % 32;
    const int tm = t / 8, tn = t % 8;
    A += (size_t)tm * 128 * 512;
    B += (size_t)batch * (HW * C_DIM) + (size_t)tn * 128 * 512;

    auto stage = [&](const u16* gbase, u16* lds, int kt) {
#pragma unroll
        for (int i = 0; i < 4; ++i) {
            int L = i * 256 + tid;
            int row = L >> 3, cs = L & 7;
            int c = cs ^ (row & 7);
            async16(gbase + (size_t)row * 512 + kt * 64 + c * 8,
                    lds + (size_t)(i * 256 + (tid & 192)) * 8);
        }
    };

    ffrag acc[4][4] = {};
    stage(A, smem, 0); stage(B, smem + 16384, 0);
    const int wr = (w >> 1) * 64, wc = (w & 1) * 64;
#pragma unroll
    for (int kt = 0; kt < 8; ++kt) {
        const int cur = kt & 1;
        asm volatile("s_waitcnt vmcnt(0)" ::: "memory");
        __builtin_amdgcn_s_barrier();
        __builtin_amdgcn_sched_barrier(0);
        if (kt < 7) {
            stage(A, smem + (cur ^ 1) * 8192, kt + 1);
            stage(B, smem + 16384 + (cur ^ 1) * 8192, kt + 1);
        }
        const u16* As = smem + cur * 8192;
        const u16* Bs = smem + 16384 + cur * 8192;
#pragma unroll
        for (int kc = 0; kc < 2; ++kc) {
            bfrag a[4], bb[4];
#pragma unroll
            for (int i = 0; i < 4; ++i) {
                int row = wr + i * 16 + (l & 15);
                int ch = (kc * 4 + (l >> 4)) ^ (row & 7);
                a[i] = *(const bfrag*)&As[row * 64 + ch * 8];
                int col = wc + i * 16 + (l & 15);
                int ch2 = (kc * 4 + (l >> 4)) ^ (col & 7);
                bb[i] = *(const bfrag*)&Bs[col * 64 + ch2 * 8];
            }
            __builtin_amdgcn_s_setprio(1);
#pragma unroll
            for (int i = 0; i < 4; ++i)
#pragma unroll
                for (int j = 0; j < 4; ++j)
                    acc[i][j] = __builtin_amdgcn_mfma_f32_16x16x32_bf16(a[i], bb[j], acc[i][j], 0, 0, 0);
            __builtin_amdgcn_s_setprio(0);
        }
    }
    const int rbase = tm * 128 + wr + ((l >> 4) << 2);
    const int cbase = tn * 128 + wc + (l & 15);
    float* outp = Out + (size_t)batch * (C_DIM * HW);
    const u16* rt = residT + (size_t)batch * (HW * C_DIM);
#pragma unroll
    for (int i = 0; i < 4; ++i)
#pragma unroll
        for (int j = 0; j < 4; ++j) {
            int cc = cbase + j * 16;                       // hw
            us4 rv = *(const us4*)&rt[(size_t)cc * C_DIM + rbase + i * 16];
#pragma unroll
            for (int r = 0; r < 4; ++r) {
                int rr = rbase + i * 16 + r;               // out channel
                outp[(size_t)rr * HW + cc] = acc[i][j][r] + bias[rr] + bf2f(rv[r]);
            }
        }
}

// ---------------- Flash attention: 2 m-tiles per barrier-step (R19 exact) -------------
__global__ __launch_bounds__(512, 4) void attn_kernel(const u16* __restrict__ qkvt,
                                                      const u16* __restrict__ vt,
                                                      u16* __restrict__ ht)
{
    __shared__ __align__(16) u16 KVs[8 * 4096];
    const int tid = threadIdx.x, l = tid & 63, w = tid >> 6, g = l >> 4;
    const int swz = ((blockIdx.x & 7) << 6) + (blockIdx.x >> 3);
    const int nt = swz & 3, h = (swz >> 2) & 7, batch = swz >> 5;
    const u16* Qb = qkvt + (size_t)batch * HW * O3 + h * 64;
    const u16* Kb = Qb + 512;
    const u16* Vtb = vt + (size_t)(batch * 8 + h) * 64 * HW;
    const int n0 = nt * 256 + w * 32;

    bfrag qf[2][2];
#pragma unroll
    for (int ni = 0; ni < 2; ++ni)
#pragma unroll
        for (int kc = 0; kc < 2; ++kc)
            qf[ni][kc] = *(const bfrag*)&Qb[(size_t)(n0 + ni * 16 + (l & 15)) * O3 + kc * 32 + g * 8];

    bfrag ones;
#pragma unroll
    for (int k = 0; k < 8; ++k) ones[k] = (short)0x3F80;   // bf16 1.0

    auto stageK = [&](int ms, u16* lds) {
        int row = tid >> 3, c = (tid & 7) ^ (row & 7);
        async16(&Kb[(size_t)(ms * 64 + row) * O3 + c * 8], lds + (size_t)(tid & 448) * 8);
    };
    auto stageV = [&](int ms, u16* lds) {
        int row = tid >> 3, c = (tid & 7) ^ (row & 7);
        async16(&Vtb[(size_t)row * HW + ms * 64 + c * 8], lds + (size_t)(tid & 448) * 8);
    };

    ffrag hacc[2][4] = {};
    ffrag accl[2] = {};

    stageK(0, KVs);        stageV(0, KVs + 4 * 4096);
    stageK(1, KVs + 4096); stageV(1, KVs + 5 * 4096);

#pragma unroll
    for (int st = 0; st < 8; ++st) {
        asm volatile("s_waitcnt vmcnt(0)" ::: "memory");
        __builtin_amdgcn_s_barrier();
        __builtin_amdgcn_sched_barrier(0);
        if (st < 7) {
            const int mt2 = 2 * st + 2, mt3 = 2 * st + 3;
            stageK(mt2, KVs + (mt2 & 3) * 4096);
            stageV(mt2, KVs + (4 + (mt2 & 3)) * 4096);
            stageK(mt3, KVs + (mt3 & 3) * 4096);
            stageV(mt3, KVs + (4 + (mt3 & 3)) * 4096);
        }
#pragma unroll
        for (int half = 0; half < 2; ++half) {
            const int mt = 2 * st + half;
            const u16* Ksc = KVs + (mt & 3) * 4096;
            const u16* Vsc = KVs + (4 + (mt & 3)) * 4096;

            ffrag s[2][4] = {};
            __builtin_amdgcn_s_setprio(1);
#pragma unroll
            for (int mj = 0; mj < 4; ++mj)
#pragma unroll
                for (int kc = 0; kc < 2; ++kc) {
                    int m = mj * 16 + (l & 15);
                    int ch = (kc * 4 + g) ^ (m & 7);
                    bfrag kf = *(const bfrag*)&Ksc[m * 64 + ch * 8];
#pragma unroll
                    for (int ni = 0; ni < 2; ++ni)
                        s[ni][mj] = __builtin_amdgcn_mfma_f32_16x16x32_bf16(kf, qf[ni][kc], s[ni][mj], 0, 0, 0);
                }
            __builtin_amdgcn_s_setprio(0);

            // S pre-scaled by cexp (folded into Q in the QKV GEMM): P = exp2(S)
            u32x4 pk[2][2];
#pragma unroll
            for (int ni = 0; ni < 2; ++ni)
#pragma unroll
                for (int kc = 0; kc < 2; ++kc)
#pragma unroll
                    for (int hh = 0; hh < 2; ++hh) {
                        int mj = kc * 2 + hh;
                        float p0 = fexp2(s[ni][mj][0]);
                        float p1 = fexp2(s[ni][mj][1]);
                        float p2 = fexp2(s[ni][mj][2]);
                        float p3 = fexp2(s[ni][mj][3]);
                        pk[ni][kc][hh * 2] = __builtin_amdgcn_perm(
                            __builtin_bit_cast(uint32_t, p1), __builtin_bit_cast(uint32_t, p0), 0x07060302u);
                        pk[ni][kc][hh * 2 + 1] = __builtin_amdgcn_perm(
                            __builtin_bit_cast(uint32_t, p3), __builtin_bit_cast(uint32_t, p2), 0x07060302u);
                    }

            __builtin_amdgcn_s_setprio(1);
#pragma unroll
            for (int kc = 0; kc < 2; ++kc) {
                bfrag pf0 = __builtin_bit_cast(bfrag, pk[0][kc]);
                bfrag pf1 = __builtin_bit_cast(bfrag, pk[1][kc]);
                accl[0] = __builtin_amdgcn_mfma_f32_16x16x32_bf16(pf0, ones, accl[0], 0, 0, 0);
                accl[1] = __builtin_amdgcn_mfma_f32_16x16x32_bf16(pf1, ones, accl[1], 0, 0, 0);
#pragma unroll
                for (int dj = 0; dj < 4; ++dj) {
                    int d = dj * 16 + (l & 15);
                    int ch = (kc * 4 + g) ^ (d & 7);
                    bfrag vf = *(const bfrag*)&Vsc[d * 64 + ch * 8];
                    hacc[0][dj] = __builtin_amdgcn_mfma_f32_16x16x32_bf16(pf0, vf, hacc[0][dj], 0, 0, 0);
                    hacc[1][dj] = __builtin_amdgcn_mfma_f32_16x16x32_bf16(pf1, vf, hacc[1][dj], 0, 0, 0);
                }
            }
            __builtin_amdgcn_s_setprio(0);
        }
    }

    // epilogue: h_t[b][n][h*64+d]
    u16* hp = ht + (size_t)batch * HW * C_DIM + h * 64;
#pragma unroll
    for (int ni = 0; ni < 2; ++ni) {
        float linv[4];
#pragma unroll
        for (int r = 0; r < 4; ++r) linv[r] = __builtin_amdgcn_rcpf(accl[ni][r]);
#pragma unroll
        for (int dj = 0; dj < 4; ++dj)
#pragma unroll
            for (int r = 0; r < 4; ++r) {
                int n = n0 + ni * 16 + g * 4 + r;
                int d = dj * 16 + (l & 15);
                hp[(size_t)n * C_DIM + d] = f2bf(hacc[ni][dj][r] * linv[r]);
            }
    }
}

extern "C" void kernel_launch(void* const* d_in, const int* in_sizes, int n_in,
                              void* d_out, int out_size, void* d_ws, size_t ws_size,
                              hipStream_t stream)
{
    const float* x = (const float*)d_in[0];
    const float* gw = (const float*)d_in[1];
    const float* gb = (const float*)d_in[2];
    const float* qkvw = (const float*)d_in[3];
    const float* projw = (const float*)d_in[4];
    const float* projb = (const float*)d_in[5];
    float* out = (float*)d_out;
    char* ws = (char*)d_ws;
    u16* ht    = (u16*)(ws);               // 16.78 MB  [B][HW][C]  attn output
    u16* xgt   = (u16*)(ws + 16777216);    // 16.78 MB  [B][HW][C]  normed x (lives to proj)
    u16* qkvt  = (u16*)(ws + 33554432);    // 50.33 MB  [B][HW][1536] (V third unused)
    u16* vt    = (u16*)(ws + 83886080);    // 16.78 MB  [B*8][64][1024] sigma-permuted cols
    u16* qkvwb = (u16*)(ws + 100663296);   // 1.57 MB
    u16* projwb= (u16*)(ws + 102236160);   // 0.52 MB

    gn_cvt_kernel<<<1536, 256, 0, stream>>>(x, gw, gb, xgt, qkvw, qkvwb, projw, projwb);
    qkv_gemm_kernel<<<1536, 256, 0, stream>>>(xgt, qkvwb, qkvt, vt);
    attn_kernel<<<512, 512, 0, stream>>>(qkvt, vt, ht);
    proj_gemm_kernel<<<512, 256, 0, stream>>>(projwb, ht, out, projb, xgt);
}